// Round 2
// baseline (250.193 us; speedup 1.0000x reference)
//
#include <hip/hip_runtime.h>
#include <hip/hip_bf16.h>

// Problem constants
#define DD 512
#define HIDN 64
#define NTREE 64
#define NIN 7           // internal nodes
#define PPTC 3607       // NI*D + NI + NL*2
#define TOTP 230912     // PPT*T + T
#define SWROWS 448      // T*NI

typedef __attribute__((ext_vector_type(8))) short bf16x8;
typedef __attribute__((ext_vector_type(4))) float f32x4;
typedef __attribute__((ext_vector_type(8))) _Float16 h16x8;

__device__ __forceinline__ unsigned short f2bf(float f) {
  unsigned u = __float_as_uint(f);
  unsigned r = (u + 0x7FFFu + ((u >> 16) & 1u)) >> 16;   // RNE
  return (unsigned short)r;
}
__device__ __forceinline__ float bf2f(unsigned short h) {
  return __uint_as_float(((unsigned)h) << 16);
}
__device__ __forceinline__ float sigmoidf_(float x) {
  return 1.0f / (1.0f + __expf(-x));
}
__device__ __forceinline__ uint2 pack_bf16x4(float4 v) {
  uint2 pk;
  pk.x = (unsigned)f2bf(v.x) | ((unsigned)f2bf(v.y) << 16);
  pk.y = (unsigned)f2bf(v.z) | ((unsigned)f2bf(v.w) << 16);
  return pk;
}

// ---------------------------------------------------------------------------
// Kernel 1: train path. Block = 256 thr (4 waves), 64 rows/block, 128 blocks.
// ---------------------------------------------------------------------------
__global__ __launch_bounds__(256) void k_train(
    const float* __restrict__ Xtr, const float* __restrict__ W1,
    const float* __restrict__ b1, const float* __restrict__ g1,
    const float* __restrict__ be1, const float* __restrict__ W2,
    const float* __restrict__ b2, float* __restrict__ c_accum)
{
  __shared__ __align__(16) char smem[49408];
  char* Xc  = smem;            // [64][128] bf16 = 16384 (K-chunk of X)
  char* W1c = smem + 16384;    // [64][128] bf16 = 16384 (K-chunk of W1)
  char* Hl  = smem + 32768;    // 4 waves * [16][64] bf16 (2048 each)
  char* W2l = smem + 40960;    // [64][64] bf16 = 8192
  float* cpart = (float*)(smem + 49152); // 64 floats

  const int tid = threadIdx.x;
  const int lane = tid & 63;
  const int wv = tid >> 6;
  const int l15 = lane & 15;
  const int gq = lane >> 4;
  const int rb0 = blockIdx.x * 64;

#pragma unroll
  for (int s = 0; s < 4; ++s) {
    int fidx = tid + s * 256;
    int n = fidx >> 4, kq = fidx & 15;
    float4 v = ((const float4*)W2)[n * 16 + kq];
    uint2 pk = pack_bf16x4(v);
    int off = n * 128 + kq * 8; off ^= (n & 7) << 4;
    *(uint2*)(W2l + off) = pk;
  }
  if (tid < 64) cpart[tid] = 0.0f;

  f32x4 acc1[4];
#pragma unroll
  for (int nt = 0; nt < 4; ++nt) { f32x4 z = {0.f,0.f,0.f,0.f}; acc1[nt] = z; }

  for (int kc = 0; kc < 4; ++kc) {
    __syncthreads();
#pragma unroll
    for (int s = 0; s < 8; ++s) {
      int idx = tid + s * 256;
      int m = idx >> 5, kq = idx & 31;
      float4 v = ((const float4*)Xtr)[(rb0 + m) * 128 + kc * 32 + kq];
      uint2 pk = pack_bf16x4(v);
      int off = m * 256 + kq * 8; off ^= (m & 7) << 4;
      *(uint2*)(Xc + off) = pk;
      float4 w = ((const float4*)W1)[m * 128 + kc * 32 + kq];
      uint2 pw = pack_bf16x4(w);
      *(uint2*)(W1c + off) = pw;
    }
    __syncthreads();
#pragma unroll
    for (int ks = 0; ks < 4; ++ks) {
      int mrow = wv * 16 + l15;
      int aoff = mrow * 256 + ks * 64 + gq * 16; aoff ^= (mrow & 7) << 4;
      bf16x8 afr = *(const bf16x8*)(Xc + aoff);
#pragma unroll
      for (int nt = 0; nt < 4; ++nt) {
        int n = nt * 16 + l15;
        int boff = n * 256 + ks * 64 + gq * 16; boff ^= (n & 7) << 4;
        bf16x8 bfr = *(const bf16x8*)(W1c + boff);
        acc1[nt] = __builtin_amdgcn_mfma_f32_16x16x32_bf16(afr, bfr, acc1[nt], 0, 0, 0);
      }
    }
  }

  float b1v[4], g1v[4], be1v[4], b2v[4];
#pragma unroll
  for (int nt = 0; nt < 4; ++nt) {
    int c = nt * 16 + l15;
    b1v[nt] = b1[c]; g1v[nt] = g1[c]; be1v[nt] = be1[c]; b2v[nt] = b2[c];
  }
  float yv[4][4], s_[4], q_[4];
#pragma unroll
  for (int i = 0; i < 4; ++i) {
    float s = 0.f, q = 0.f;
#pragma unroll
    for (int nt = 0; nt < 4; ++nt) {
      float y = acc1[nt][i] + b1v[nt];
      yv[nt][i] = y; s += y; q += y * y;
    }
    s_[i] = s; q_[i] = q;
  }
#pragma unroll
  for (int off = 1; off < 16; off <<= 1) {
#pragma unroll
    for (int i = 0; i < 4; ++i) {
      s_[i] += __shfl_xor(s_[i], off);
      q_[i] += __shfl_xor(q_[i], off);
    }
  }
  char* Hw = Hl + wv * 2048;
#pragma unroll
  for (int i = 0; i < 4; ++i) {
    float m = s_[i] * (1.0f / 64.0f);
    float var = q_[i] * (1.0f / 64.0f) - m * m;
    float rstd = rsqrtf(var + 1e-5f);
    int mrow = gq * 4 + i;
#pragma unroll
    for (int nt = 0; nt < 4; ++nt) {
      float h = (yv[nt][i] - m) * rstd * g1v[nt] + be1v[nt];
      h = fmaxf(h, 0.0f);
      int col = nt * 16 + l15;
      int off2 = mrow * 128 + col * 2; off2 ^= (mrow & 7) << 4;
      *(unsigned short*)(Hw + off2) = f2bf(h);
    }
  }
  __syncthreads();

  f32x4 acc2[4];
#pragma unroll
  for (int nt = 0; nt < 4; ++nt) { f32x4 z = {0.f,0.f,0.f,0.f}; acc2[nt] = z; }
#pragma unroll
  for (int ks = 0; ks < 2; ++ks) {
    int aoff = l15 * 128 + ks * 64 + gq * 16; aoff ^= (l15 & 7) << 4;
    bf16x8 afr = *(const bf16x8*)(Hw + aoff);
#pragma unroll
    for (int nt = 0; nt < 4; ++nt) {
      int n = nt * 16 + l15;
      int boff = n * 128 + ks * 64 + gq * 16; boff ^= (n & 7) << 4;
      bf16x8 bfr = *(const bf16x8*)(W2l + boff);
      acc2[nt] = __builtin_amdgcn_mfma_f32_16x16x32_bf16(afr, bfr, acc2[nt], 0, 0, 0);
    }
  }
  float cs[4];
#pragma unroll
  for (int nt = 0; nt < 4; ++nt) {
    float s = 0.f;
#pragma unroll
    for (int i = 0; i < 4; ++i) {
      float z = acc2[nt][i] + b2v[nt];
      s += fmaxf(z, 0.0f);
    }
    cs[nt] = s;
  }
#pragma unroll
  for (int nt = 0; nt < 4; ++nt) {
    cs[nt] += __shfl_xor(cs[nt], 16);
    cs[nt] += __shfl_xor(cs[nt], 32);
  }
  if (lane < 16) {
#pragma unroll
    for (int nt = 0; nt < 4; ++nt) atomicAdd(&cpart[nt * 16 + l15], cs[nt]);
  }
  __syncthreads();
  if (tid < 64) atomicAdd(&c_accum[tid], cpart[tid]);
}

// ---------------------------------------------------------------------------
// Kernel 2: head MLP (fp32, tiny). 1 block x 128 threads.
// ---------------------------------------------------------------------------
__global__ __launch_bounds__(128) void k_head(
    const float* __restrict__ c_accum,
    const float* __restrict__ H1, const float* __restrict__ hb1,
    const float* __restrict__ g2, const float* __restrict__ be2,
    const float* __restrict__ H2, const float* __restrict__ hb2,
    float* __restrict__ u2out)
{
  __shared__ float clds[64];
  __shared__ float u1lds[128];
  __shared__ float red[4];
  int tid = threadIdx.x;
  if (tid < 64) clds[tid] = c_accum[tid] * (1.0f / 8192.0f);
  __syncthreads();
  float acc = hb1[tid];
  for (int k = 0; k < 64; ++k) acc += clds[k] * H1[tid * 64 + k];
  float s = acc, q = acc * acc;
#pragma unroll
  for (int off = 1; off < 64; off <<= 1) { s += __shfl_xor(s, off); q += __shfl_xor(q, off); }
  int wv = tid >> 6;
  if ((tid & 63) == 0) { red[wv * 2] = s; red[wv * 2 + 1] = q; }
  __syncthreads();
  float S = red[0] + red[2], Q = red[1] + red[3];
  float m = S * (1.0f / 128.0f);
  float var = Q * (1.0f / 128.0f) - m * m;
  float rstd = rsqrtf(var + 1e-5f);
  float u1 = fmaxf((acc - m) * rstd * g2[tid] + be2[tid], 0.0f);
  u1lds[tid] = u1;
  __syncthreads();
  float a2 = hb2[tid];
  for (int k = 0; k < 128; ++k) a2 += u1lds[k] * H2[tid * 128 + k];
  u2out[tid] = fmaxf(a2, 0.0f);
}

// ---------------------------------------------------------------------------
// Kernel 3: params = u2 @ H3^T + hb3, routed to sw(bf16)/sb/ll/tw.
// ---------------------------------------------------------------------------
__global__ __launch_bounds__(256) void k_params(
    const float* __restrict__ H3, const float* __restrict__ hb3,
    const float* __restrict__ u2,
    unsigned short* __restrict__ Bsw, float* __restrict__ sb,
    float* __restrict__ ll, float* __restrict__ tw)
{
  __shared__ float u2l[128];
  int tid = threadIdx.x;
  if (tid < 128) u2l[tid] = u2[tid];
  __syncthreads();
  int row = blockIdx.x * 64 + (tid >> 2);
  int sub = tid & 3;
  float acc = 0.0f;
  const float4* H4 = (const float4*)H3;
#pragma unroll
  for (int j = 0; j < 8; ++j) {
    int f = j * 4 + sub;
    float4 v = H4[row * 32 + f];
    acc += v.x * u2l[f * 4] + v.y * u2l[f * 4 + 1] + v.z * u2l[f * 4 + 2] + v.w * u2l[f * 4 + 3];
  }
  acc += __shfl_xor(acc, 1);
  acc += __shfl_xor(acc, 2);
  if (sub == 0) {
    float val = acc + hb3[row];
    if (row >= 230848) {
      tw[row - 230848] = val;
    } else {
      int t = row / PPTC;
      int r = row - t * PPTC;
      if (r < 3584) {
        int n = r >> 9, d = r & 511;
        Bsw[(t * 7 + n) * 512 + d] = f2bf(val);
      } else if (r < 3591) {
        sb[t * 7 + (r - 3584)] = val;
      } else {
        ll[t * 16 + (r - 3591)] = val;
      }
    }
  }
}

// ---------------------------------------------------------------------------
// Kernel 4: q[t][l][c] = 2 * softmax(tw)[t] * softmax(ll[t,l,:])[c]
// ---------------------------------------------------------------------------
__global__ __launch_bounds__(64) void k_qprep(
    const float* __restrict__ ll, const float* __restrict__ tw,
    float* __restrict__ q)
{
  int t = threadIdx.x;
  float x = tw[t];
  float m = x;
#pragma unroll
  for (int off = 1; off < 64; off <<= 1) m = fmaxf(m, __shfl_xor(m, off));
  float e = __expf(x - m);
  float s = e;
#pragma unroll
  for (int off = 1; off < 64; off <<= 1) s += __shfl_xor(s, off);
  float w = e / s;
#pragma unroll
  for (int l = 0; l < 8; ++l) {
    float a = ll[t * 16 + l * 2], b = ll[t * 16 + l * 2 + 1];
    float mm = fmaxf(a, b);
    float e0 = __expf(a - mm), e1 = __expf(b - mm);
    float inv = 2.0f * w / (e0 + e1);
    q[t * 16 + l * 2] = e0 * inv;
    q[t * 16 + l * 2 + 1] = e1 * inv;
  }
}

// ---------------------------------------------------------------------------
// Kernel 5: main inference. Block = 512 thr (8 waves), BM=128, BN=448, BK=32.
// grid = 256 (1 block/CU). Wave grid 2M x 4N: each wave 64 rows x 112 cols.
// Reg-pipelined staging (T14): issue kt+1 loads between barriers of kt.
// Tree phase: p in fp16 LDS, 8 slots/tree -> 1 ds_read_b128 per (row,tree);
// q in registers (t = lane); shuffle-butterfly reduce over trees; no atomics.
// ---------------------------------------------------------------------------
__global__ __launch_bounds__(512) void k_test(
    const float* __restrict__ Xt, const unsigned short* __restrict__ Bsw,
    const float* __restrict__ sb, const float* __restrict__ q,
    float* __restrict__ out)
{
  __shared__ __align__(16) char smem[39680];
  char* Xl = smem;                        // [128][32] bf16 = 8192
  char* Bl = smem + 8192;                 // [448][32] bf16 = 28672 -> 36864
  char* Pl = smem;                        // pass p tile: 32 rows x 1024 B (alias)
  float* sbl  = (float*)(smem + 36864);   // 448 floats -> 38656
  float* outl = (float*)(smem + 38656);   // 256 floats -> 39680

  const int tid = threadIdx.x;
  const int lane = tid & 63;
  const int wv = tid >> 6;
  const int l15 = lane & 15;
  const int gq = lane >> 4;
  const int wm = wv >> 2;        // 0..1 (64-row group)
  const int wn = wv & 3;         // 0..3 (112-col group)
  const int bm0 = blockIdx.x * 128;

  if (tid < 448) sbl[tid] = sb[tid];

  // q registers: this thread's tree t = lane, 16 values
  float qreg[16];
  {
    const float4* q4 = (const float4*)q;
#pragma unroll
    for (int j = 0; j < 4; ++j) {
      float4 v = q4[lane * 4 + j];
      qreg[j * 4] = v.x; qreg[j * 4 + 1] = v.y; qreg[j * 4 + 2] = v.z; qreg[j * 4 + 3] = v.w;
    }
  }

  // ---- staging address precompute (per-thread constants) ----
  const int xm = tid >> 3, xk = tid & 7;            // X: 2 float4 per thread
  const int xg0 = (bm0 + xm) * 128 + xk;            // + kt*8
  const int xg1 = (bm0 + xm + 64) * 128 + xk;
  int xo0 = xm * 64 + xk * 8;        xo0 ^= (xm & 7) << 4;
  int xo1 = (xm + 64) * 64 + xk * 8; xo1 ^= (xm & 7) << 4;

  int bg[4], bo[4];                                  // B: 4 uint4 per thread
#pragma unroll
  for (int s = 0; s < 4; ++s) {
    int idx = tid + s * 512; if (idx > 1791) idx = 1791;
    int n = idx >> 2, part = idx & 3;
    bg[s] = n * 64 + part;                           // + kt*4
    bo[s] = (n * 64 + part * 16) ^ ((n & 7) << 4);
  }

  // ---- frag read offsets (per-thread constants) ----
  int aoffs[4], boffs[7];
#pragma unroll
  for (int mt = 0; mt < 4; ++mt) {
    int r = wm * 64 + mt * 16 + l15;
    aoffs[mt] = (r * 64 + gq * 16) ^ ((r & 7) << 4);
  }
#pragma unroll
  for (int nt = 0; nt < 7; ++nt) {
    int r = wn * 112 + nt * 16 + l15;
    boffs[nt] = (r * 64 + gq * 16) ^ ((r & 7) << 4);
  }

  f32x4 acc[4][7];
#pragma unroll
  for (int mt = 0; mt < 4; ++mt)
#pragma unroll
    for (int nt = 0; nt < 7; ++nt) { f32x4 z = {0.f,0.f,0.f,0.f}; acc[mt][nt] = z; }

  const float4* X4 = (const float4*)Xt;
  const uint4* B4 = (const uint4*)Bsw;

  // prologue: load kt=0 into regs
  float4 xr0 = X4[xg0], xr1 = X4[xg1];
  uint4 br0 = B4[bg[0]], br1 = B4[bg[1]], br2 = B4[bg[2]], br3 = B4[bg[3]];

  for (int kt = 0; kt < 16; ++kt) {
    __syncthreads();   // previous iter's frag reads complete
    *(uint2*)(Xl + xo0) = pack_bf16x4(xr0);
    *(uint2*)(Xl + xo1) = pack_bf16x4(xr1);
    *(uint4*)(Bl + bo[0]) = br0;
    *(uint4*)(Bl + bo[1]) = br1;
    *(uint4*)(Bl + bo[2]) = br2;
    *(uint4*)(Bl + bo[3]) = br3;
    if (kt < 15) {      // issue next-iter loads; latency hides under compute
      int k8 = (kt + 1) * 8, k4 = (kt + 1) * 4;
      xr0 = X4[xg0 + k8]; xr1 = X4[xg1 + k8];
      br0 = B4[bg[0] + k4]; br1 = B4[bg[1] + k4];
      br2 = B4[bg[2] + k4]; br3 = B4[bg[3] + k4];
    }
    __syncthreads();   // tile ready
    bf16x8 afr[4];
#pragma unroll
    for (int mt = 0; mt < 4; ++mt) afr[mt] = *(const bf16x8*)(Xl + aoffs[mt]);
#pragma unroll
    for (int nt = 0; nt < 7; ++nt) {
      bf16x8 bfr = *(const bf16x8*)(Bl + boffs[nt]);
#pragma unroll
      for (int mt = 0; mt < 4; ++mt)
        acc[mt][nt] = __builtin_amdgcn_mfma_f32_16x16x32_bf16(afr[mt], bfr, acc[mt][nt], 0, 0, 0);
    }
  }
  __syncthreads();   // all GEMM LDS reads done; Pl aliases staging region

  // ---- fused sigmoid + soft-tree + leaf/tree mixing, 4 passes of 32 rows ----
#pragma unroll 1
  for (int rg = 0; rg < 4; ++rg) {
    if (wm == (rg >> 1)) {
#pragma unroll
      for (int mtl = 0; mtl < 2; ++mtl) {
        int mt = (rg & 1) * 2 + mtl;
#pragma unroll
        for (int nt = 0; nt < 7; ++nt) {
          int col = wn * 112 + nt * 16 + l15;
          float sbv = sbl[col];
          int t = col / 7;                 // magic-mul
          int j = col - t * 7;
          int slot2 = (t * 8 + j) * 2;
#pragma unroll
          for (int i = 0; i < 4; ++i) {
            int rl = mtl * 16 + gq * 4 + i;
            float p = sigmoidf_(acc[mt][nt][i] + sbv);
            *(_Float16*)(Pl + rl * 1024 + slot2) = (_Float16)p;
          }
        }
      }
    }
    __syncthreads();
    // tree: this wave handles rows wv*4 .. wv*4+3 of the pass; tree t = lane
#pragma unroll
    for (int k = 0; k < 4; ++k) {
      int rl = wv * 4 + k;
      h16x8 v = *(const h16x8*)(Pl + rl * 1024 + lane * 16);
      float p0 = (float)v[0], p1 = (float)v[1], p2 = (float)v[2];
      float p3 = (float)v[3], p4 = (float)v[4], p5 = (float)v[5], p6 = (float)v[6];
      float n0 = 1.f - p0, n1 = 1.f - p1, n2 = 1.f - p2;
      float a00 = n0 * n1, a01 = n0 * p1, a10 = p0 * n2, a11 = p0 * p2;
      float L0 = a00 * (1.f - p3), L1 = a00 * p3;
      float L2 = a01 * (1.f - p4), L3 = a01 * p4;
      float L4 = a10 * (1.f - p5), L5 = a10 * p5;
      float L6 = a11 * (1.f - p6), L7 = a11 * p6;
      float o0 = L0*qreg[0] + L1*qreg[2] + L2*qreg[4] + L3*qreg[6]
               + L4*qreg[8] + L5*qreg[10] + L6*qreg[12] + L7*qreg[14];
      float o1 = L0*qreg[1] + L1*qreg[3] + L2*qreg[5] + L3*qreg[7]
               + L4*qreg[9] + L5*qreg[11] + L6*qreg[13] + L7*qreg[15];
#pragma unroll
      for (int off = 1; off < 64; off <<= 1) {
        o0 += __shfl_xor(o0, off);
        o1 += __shfl_xor(o1, off);
      }
      if (lane == 0) {
        int gr = rg * 32 + rl;
        outl[gr * 2] = o0;
        outl[gr * 2 + 1] = o1;
      }
    }
    __syncthreads();   // tree reads done before next pass overwrites Pl
  }
  if (tid < 256) out[bm0 * 2 + tid] = outl[tid];
}

// ---------------------------------------------------------------------------
extern "C" void kernel_launch(void* const* d_in, const int* in_sizes, int n_in,
                              void* d_out, int out_size, void* d_ws, size_t ws_size,
                              hipStream_t stream)
{
  const float* Xtr = (const float*)d_in[0];
  const float* Xte = (const float*)d_in[1];
  const float* W1  = (const float*)d_in[3];
  const float* b1  = (const float*)d_in[4];
  const float* g1  = (const float*)d_in[5];
  const float* be1 = (const float*)d_in[6];
  const float* W2  = (const float*)d_in[7];
  const float* b2  = (const float*)d_in[8];
  const float* H1  = (const float*)d_in[9];
  const float* hb1 = (const float*)d_in[10];
  const float* g2  = (const float*)d_in[11];
  const float* be2 = (const float*)d_in[12];
  const float* H2  = (const float*)d_in[13];
  const float* hb2 = (const float*)d_in[14];
  const float* H3  = (const float*)d_in[15];
  const float* hb3 = (const float*)d_in[16];
  float* out = (float*)d_out;
  char* ws = (char*)d_ws;

  float* c_accum = (float*)ws;                 // 64 f32
  float* u2      = (float*)(ws + 256);         // 128 f32
  float* sb      = (float*)(ws + 768);         // 448 f32
  float* ll      = (float*)(ws + 2560);        // 1024 f32
  float* tw      = (float*)(ws + 6656);        // 64 f32
  float* q       = (float*)(ws + 6912);        // 1024 f32
  unsigned short* Bsw = (unsigned short*)(ws + 11008); // 448*512 bf16

  hipMemsetAsync(c_accum, 0, 64 * sizeof(float), stream);
  k_train<<<128, 256, 0, stream>>>(Xtr, W1, b1, g1, be1, W2, b2, c_accum);
  k_head<<<1, 128, 0, stream>>>(c_accum, H1, hb1, g2, be2, H2, hb2, u2);
  k_params<<<3608, 256, 0, stream>>>(H3, hb3, u2, Bsw, sb, ll, tw);
  k_qprep<<<1, 64, 0, stream>>>(ll, tw, q);
  k_test<<<256, 512, 0, stream>>>(Xte, Bsw, sb, q, out);
}

// Round 3
// 96.288 us; speedup vs baseline: 2.5984x; 2.5984x over previous
//
#include <hip/hip_runtime.h>
#include <hip/hip_bf16.h>

// Problem constants
#define DD 512
#define HIDN 64
#define NTREE 64
#define NIN 7           // internal nodes
#define PPTC 3607       // NI*D + NI + NL*2
#define TOTP 230912     // PPT*T + T
#define SWROWS 448      // T*NI

typedef __attribute__((ext_vector_type(8))) short bf16x8;
typedef __attribute__((ext_vector_type(4))) float f32x4;
typedef __attribute__((ext_vector_type(8))) _Float16 h16x8;

__device__ __forceinline__ unsigned short f2bf(float f) {
  unsigned u = __float_as_uint(f);
  unsigned r = (u + 0x7FFFu + ((u >> 16) & 1u)) >> 16;   // RNE
  return (unsigned short)r;
}
__device__ __forceinline__ float bf2f(unsigned short h) {
  return __uint_as_float(((unsigned)h) << 16);
}
__device__ __forceinline__ float sigmoidf_(float x) {
  return 1.0f / (1.0f + __expf(-x));
}
__device__ __forceinline__ uint2 pack_bf16x4(float4 v) {
  uint2 pk;
  pk.x = (unsigned)f2bf(v.x) | ((unsigned)f2bf(v.y) << 16);
  pk.y = (unsigned)f2bf(v.z) | ((unsigned)f2bf(v.w) << 16);
  return pk;
}

// ---------------------------------------------------------------------------
// Kernel 1: train path. Block = 256 thr (4 waves), 64 rows/block, 128 blocks.
// ---------------------------------------------------------------------------
__global__ __launch_bounds__(256) void k_train(
    const float* __restrict__ Xtr, const float* __restrict__ W1,
    const float* __restrict__ b1, const float* __restrict__ g1,
    const float* __restrict__ be1, const float* __restrict__ W2,
    const float* __restrict__ b2, float* __restrict__ c_accum)
{
  __shared__ __align__(16) char smem[49408];
  char* Xc  = smem;            // [64][128] bf16 = 16384 (K-chunk of X)
  char* W1c = smem + 16384;    // [64][128] bf16 = 16384 (K-chunk of W1)
  char* Hl  = smem + 32768;    // 4 waves * [16][64] bf16 (2048 each)
  char* W2l = smem + 40960;    // [64][64] bf16 = 8192
  float* cpart = (float*)(smem + 49152); // 64 floats

  const int tid = threadIdx.x;
  const int lane = tid & 63;
  const int wv = tid >> 6;
  const int l15 = lane & 15;
  const int gq = lane >> 4;
  const int rb0 = blockIdx.x * 64;

#pragma unroll
  for (int s = 0; s < 4; ++s) {
    int fidx = tid + s * 256;
    int n = fidx >> 4, kq = fidx & 15;
    float4 v = ((const float4*)W2)[n * 16 + kq];
    uint2 pk = pack_bf16x4(v);
    int off = n * 128 + kq * 8; off ^= (n & 7) << 4;
    *(uint2*)(W2l + off) = pk;
  }
  if (tid < 64) cpart[tid] = 0.0f;

  f32x4 acc1[4];
#pragma unroll
  for (int nt = 0; nt < 4; ++nt) { f32x4 z = {0.f,0.f,0.f,0.f}; acc1[nt] = z; }

  for (int kc = 0; kc < 4; ++kc) {
    __syncthreads();
#pragma unroll
    for (int s = 0; s < 8; ++s) {
      int idx = tid + s * 256;
      int m = idx >> 5, kq = idx & 31;
      float4 v = ((const float4*)Xtr)[(rb0 + m) * 128 + kc * 32 + kq];
      uint2 pk = pack_bf16x4(v);
      int off = m * 256 + kq * 8; off ^= (m & 7) << 4;
      *(uint2*)(Xc + off) = pk;
      float4 w = ((const float4*)W1)[m * 128 + kc * 32 + kq];
      uint2 pw = pack_bf16x4(w);
      *(uint2*)(W1c + off) = pw;
    }
    __syncthreads();
#pragma unroll
    for (int ks = 0; ks < 4; ++ks) {
      int mrow = wv * 16 + l15;
      int aoff = mrow * 256 + ks * 64 + gq * 16; aoff ^= (mrow & 7) << 4;
      bf16x8 afr = *(const bf16x8*)(Xc + aoff);
#pragma unroll
      for (int nt = 0; nt < 4; ++nt) {
        int n = nt * 16 + l15;
        int boff = n * 256 + ks * 64 + gq * 16; boff ^= (n & 7) << 4;
        bf16x8 bfr = *(const bf16x8*)(W1c + boff);
        acc1[nt] = __builtin_amdgcn_mfma_f32_16x16x32_bf16(afr, bfr, acc1[nt], 0, 0, 0);
      }
    }
  }

  float b1v[4], g1v[4], be1v[4], b2v[4];
#pragma unroll
  for (int nt = 0; nt < 4; ++nt) {
    int c = nt * 16 + l15;
    b1v[nt] = b1[c]; g1v[nt] = g1[c]; be1v[nt] = be1[c]; b2v[nt] = b2[c];
  }
  float yv[4][4], s_[4], q_[4];
#pragma unroll
  for (int i = 0; i < 4; ++i) {
    float s = 0.f, q = 0.f;
#pragma unroll
    for (int nt = 0; nt < 4; ++nt) {
      float y = acc1[nt][i] + b1v[nt];
      yv[nt][i] = y; s += y; q += y * y;
    }
    s_[i] = s; q_[i] = q;
  }
#pragma unroll
  for (int off = 1; off < 16; off <<= 1) {
#pragma unroll
    for (int i = 0; i < 4; ++i) {
      s_[i] += __shfl_xor(s_[i], off);
      q_[i] += __shfl_xor(q_[i], off);
    }
  }
  char* Hw = Hl + wv * 2048;
#pragma unroll
  for (int i = 0; i < 4; ++i) {
    float m = s_[i] * (1.0f / 64.0f);
    float var = q_[i] * (1.0f / 64.0f) - m * m;
    float rstd = rsqrtf(var + 1e-5f);
    int mrow = gq * 4 + i;
#pragma unroll
    for (int nt = 0; nt < 4; ++nt) {
      float h = (yv[nt][i] - m) * rstd * g1v[nt] + be1v[nt];
      h = fmaxf(h, 0.0f);
      int col = nt * 16 + l15;
      int off2 = mrow * 128 + col * 2; off2 ^= (mrow & 7) << 4;
      *(unsigned short*)(Hw + off2) = f2bf(h);
    }
  }
  __syncthreads();

  f32x4 acc2[4];
#pragma unroll
  for (int nt = 0; nt < 4; ++nt) { f32x4 z = {0.f,0.f,0.f,0.f}; acc2[nt] = z; }
#pragma unroll
  for (int ks = 0; ks < 2; ++ks) {
    int aoff = l15 * 128 + ks * 64 + gq * 16; aoff ^= (l15 & 7) << 4;
    bf16x8 afr = *(const bf16x8*)(Hw + aoff);
#pragma unroll
    for (int nt = 0; nt < 4; ++nt) {
      int n = nt * 16 + l15;
      int boff = n * 128 + ks * 64 + gq * 16; boff ^= (n & 7) << 4;
      bf16x8 bfr = *(const bf16x8*)(W2l + boff);
      acc2[nt] = __builtin_amdgcn_mfma_f32_16x16x32_bf16(afr, bfr, acc2[nt], 0, 0, 0);
    }
  }
  float cs[4];
#pragma unroll
  for (int nt = 0; nt < 4; ++nt) {
    float s = 0.f;
#pragma unroll
    for (int i = 0; i < 4; ++i) {
      float z = acc2[nt][i] + b2v[nt];
      s += fmaxf(z, 0.0f);
    }
    cs[nt] = s;
  }
#pragma unroll
  for (int nt = 0; nt < 4; ++nt) {
    cs[nt] += __shfl_xor(cs[nt], 16);
    cs[nt] += __shfl_xor(cs[nt], 32);
  }
  if (lane < 16) {
#pragma unroll
    for (int nt = 0; nt < 4; ++nt) atomicAdd(&cpart[nt * 16 + l15], cs[nt]);
  }
  __syncthreads();
  if (tid < 64) atomicAdd(&c_accum[tid], cpart[tid]);
}

// ---------------------------------------------------------------------------
// Kernel 2: head MLP (fp32, tiny). 1 block x 128 threads.
// ---------------------------------------------------------------------------
__global__ __launch_bounds__(128) void k_head(
    const float* __restrict__ c_accum,
    const float* __restrict__ H1, const float* __restrict__ hb1,
    const float* __restrict__ g2, const float* __restrict__ be2,
    const float* __restrict__ H2, const float* __restrict__ hb2,
    float* __restrict__ u2out)
{
  __shared__ float clds[64];
  __shared__ float u1lds[128];
  __shared__ float red[4];
  int tid = threadIdx.x;
  if (tid < 64) clds[tid] = c_accum[tid] * (1.0f / 8192.0f);
  __syncthreads();
  float acc = hb1[tid];
  for (int k = 0; k < 64; ++k) acc += clds[k] * H1[tid * 64 + k];
  float s = acc, q = acc * acc;
#pragma unroll
  for (int off = 1; off < 64; off <<= 1) { s += __shfl_xor(s, off); q += __shfl_xor(q, off); }
  int wv = tid >> 6;
  if ((tid & 63) == 0) { red[wv * 2] = s; red[wv * 2 + 1] = q; }
  __syncthreads();
  float S = red[0] + red[2], Q = red[1] + red[3];
  float m = S * (1.0f / 128.0f);
  float var = Q * (1.0f / 128.0f) - m * m;
  float rstd = rsqrtf(var + 1e-5f);
  float u1 = fmaxf((acc - m) * rstd * g2[tid] + be2[tid], 0.0f);
  u1lds[tid] = u1;
  __syncthreads();
  float a2 = hb2[tid];
  for (int k = 0; k < 128; ++k) a2 += u1lds[k] * H2[tid * 128 + k];
  u2out[tid] = fmaxf(a2, 0.0f);
}

// ---------------------------------------------------------------------------
// Kernel 3: params = u2 @ H3^T + hb3, routed to sw(bf16)/sb/ll/tw.
// ---------------------------------------------------------------------------
__global__ __launch_bounds__(256) void k_params(
    const float* __restrict__ H3, const float* __restrict__ hb3,
    const float* __restrict__ u2,
    unsigned short* __restrict__ Bsw, float* __restrict__ sb,
    float* __restrict__ ll, float* __restrict__ tw)
{
  __shared__ float u2l[128];
  int tid = threadIdx.x;
  if (tid < 128) u2l[tid] = u2[tid];
  __syncthreads();
  int row = blockIdx.x * 64 + (tid >> 2);
  int sub = tid & 3;
  float acc = 0.0f;
  const float4* H4 = (const float4*)H3;
#pragma unroll
  for (int j = 0; j < 8; ++j) {
    int f = j * 4 + sub;
    float4 v = H4[row * 32 + f];
    acc += v.x * u2l[f * 4] + v.y * u2l[f * 4 + 1] + v.z * u2l[f * 4 + 2] + v.w * u2l[f * 4 + 3];
  }
  acc += __shfl_xor(acc, 1);
  acc += __shfl_xor(acc, 2);
  if (sub == 0) {
    float val = acc + hb3[row];
    if (row >= 230848) {
      tw[row - 230848] = val;
    } else {
      int t = row / PPTC;
      int r = row - t * PPTC;
      if (r < 3584) {
        int n = r >> 9, d = r & 511;
        Bsw[(t * 7 + n) * 512 + d] = f2bf(val);
      } else if (r < 3591) {
        sb[t * 7 + (r - 3584)] = val;
      } else {
        ll[t * 16 + (r - 3591)] = val;
      }
    }
  }
}

// ---------------------------------------------------------------------------
// Kernel 4: q[t][l][c] = 2 * softmax(tw)[t] * softmax(ll[t,l,:])[c]
// ---------------------------------------------------------------------------
__global__ __launch_bounds__(64) void k_qprep(
    const float* __restrict__ ll, const float* __restrict__ tw,
    float* __restrict__ q)
{
  int t = threadIdx.x;
  float x = tw[t];
  float m = x;
#pragma unroll
  for (int off = 1; off < 64; off <<= 1) m = fmaxf(m, __shfl_xor(m, off));
  float e = __expf(x - m);
  float s = e;
#pragma unroll
  for (int off = 1; off < 64; off <<= 1) s += __shfl_xor(s, off);
  float w = e / s;
#pragma unroll
  for (int l = 0; l < 8; ++l) {
    float a = ll[t * 16 + l * 2], b = ll[t * 16 + l * 2 + 1];
    float mm = fmaxf(a, b);
    float e0 = __expf(a - mm), e1 = __expf(b - mm);
    float inv = 2.0f * w / (e0 + e1);
    q[t * 16 + l * 2] = e0 * inv;
    q[t * 16 + l * 2 + 1] = e1 * inv;
  }
}

// ---------------------------------------------------------------------------
// Kernel 5: main inference. Block = 512 thr (8 waves), BM=128, BN=448, BK=32.
// grid = 256 (1 block/CU). Wave grid 2M x 4N: each wave 64 rows x 112 cols.
// Reg-pipelined staging; epilogue FULLY UNROLLED so acc[][] stays in VGPRs
// (rule #20: runtime-indexed ext_vector arrays demote to scratch — that was
// round 2's 973 MB WRITE_SIZE regression).
// ---------------------------------------------------------------------------
__global__ __launch_bounds__(512) void k_test(
    const float* __restrict__ Xt, const unsigned short* __restrict__ Bsw,
    const float* __restrict__ sb, const float* __restrict__ q,
    float* __restrict__ out)
{
  __shared__ __align__(16) char smem[39680];
  char* Xl = smem;                        // [128][32] bf16 = 8192
  char* Bl = smem + 8192;                 // [448][32] bf16 = 28672 -> 36864
  char* Pl = smem;                        // pass p tile: 32 rows x 1024 B (alias)
  float* sbl  = (float*)(smem + 36864);   // 448 floats -> 38656
  float* outl = (float*)(smem + 38656);   // 256 floats -> 39680

  const int tid = threadIdx.x;
  const int lane = tid & 63;
  const int wv = tid >> 6;
  const int l15 = lane & 15;
  const int gq = lane >> 4;
  const int wm = wv >> 2;        // 0..1 (64-row group)
  const int wn = wv & 3;         // 0..3 (112-col group)
  const int bm0 = blockIdx.x * 128;

  if (tid < 448) sbl[tid] = sb[tid];

  // q registers: this thread's tree t = lane, 16 values
  float qreg[16];
  {
    const float4* q4 = (const float4*)q;
#pragma unroll
    for (int j = 0; j < 4; ++j) {
      float4 v = q4[lane * 4 + j];
      qreg[j * 4] = v.x; qreg[j * 4 + 1] = v.y; qreg[j * 4 + 2] = v.z; qreg[j * 4 + 3] = v.w;
    }
  }

  // ---- staging address precompute (per-thread constants) ----
  const int xm = tid >> 3, xk = tid & 7;            // X: 2 float4 per thread
  const int xg0 = (bm0 + xm) * 128 + xk;            // + kt*8
  const int xg1 = (bm0 + xm + 64) * 128 + xk;
  int xo0 = xm * 64 + xk * 8;        xo0 ^= (xm & 7) << 4;
  int xo1 = (xm + 64) * 64 + xk * 8; xo1 ^= (xm & 7) << 4;

  int bg[4], bo[4];                                  // B: 4 uint4 per thread
#pragma unroll
  for (int s = 0; s < 4; ++s) {
    int idx = tid + s * 512; if (idx > 1791) idx = 1791;
    int n = idx >> 2, part = idx & 3;
    bg[s] = n * 64 + part;                           // + kt*4
    bo[s] = (n * 64 + part * 16) ^ ((n & 7) << 4);
  }

  // ---- frag read offsets (per-thread constants) ----
  int aoffs[4], boffs[7];
#pragma unroll
  for (int mt = 0; mt < 4; ++mt) {
    int r = wm * 64 + mt * 16 + l15;
    aoffs[mt] = (r * 64 + gq * 16) ^ ((r & 7) << 4);
  }
#pragma unroll
  for (int nt = 0; nt < 7; ++nt) {
    int r = wn * 112 + nt * 16 + l15;
    boffs[nt] = (r * 64 + gq * 16) ^ ((r & 7) << 4);
  }

  f32x4 acc[4][7];
#pragma unroll
  for (int mt = 0; mt < 4; ++mt)
#pragma unroll
    for (int nt = 0; nt < 7; ++nt) { f32x4 z = {0.f,0.f,0.f,0.f}; acc[mt][nt] = z; }

  const float4* X4 = (const float4*)Xt;
  const uint4* B4 = (const uint4*)Bsw;

  // prologue: load kt=0 into regs
  float4 xr0 = X4[xg0], xr1 = X4[xg1];
  uint4 br0 = B4[bg[0]], br1 = B4[bg[1]], br2 = B4[bg[2]], br3 = B4[bg[3]];

  for (int kt = 0; kt < 16; ++kt) {
    __syncthreads();   // previous iter's frag reads complete
    *(uint2*)(Xl + xo0) = pack_bf16x4(xr0);
    *(uint2*)(Xl + xo1) = pack_bf16x4(xr1);
    *(uint4*)(Bl + bo[0]) = br0;
    *(uint4*)(Bl + bo[1]) = br1;
    *(uint4*)(Bl + bo[2]) = br2;
    *(uint4*)(Bl + bo[3]) = br3;
    if (kt < 15) {      // issue next-iter loads; latency hides under compute
      int k8 = (kt + 1) * 8, k4 = (kt + 1) * 4;
      xr0 = X4[xg0 + k8]; xr1 = X4[xg1 + k8];
      br0 = B4[bg[0] + k4]; br1 = B4[bg[1] + k4];
      br2 = B4[bg[2] + k4]; br3 = B4[bg[3] + k4];
    }
    __syncthreads();   // tile ready
    bf16x8 afr[4];
#pragma unroll
    for (int mt = 0; mt < 4; ++mt) afr[mt] = *(const bf16x8*)(Xl + aoffs[mt]);
#pragma unroll
    for (int nt = 0; nt < 7; ++nt) {
      bf16x8 bfr = *(const bf16x8*)(Bl + boffs[nt]);
#pragma unroll
      for (int mt = 0; mt < 4; ++mt)
        acc[mt][nt] = __builtin_amdgcn_mfma_f32_16x16x32_bf16(afr[mt], bfr, acc[mt][nt], 0, 0, 0);
    }
  }
  __syncthreads();   // all GEMM LDS reads done; Pl aliases staging region

  // ---- fused sigmoid + soft-tree + leaf/tree mixing, 4 passes of 32 rows.
  // FULL unroll: rg compile-time so acc indices are static (stays in VGPRs).
#pragma unroll
  for (int rg = 0; rg < 4; ++rg) {
    if (wm == (rg >> 1)) {
#pragma unroll
      for (int mtl = 0; mtl < 2; ++mtl) {
        const int mt = (rg & 1) * 2 + mtl;
#pragma unroll
        for (int nt = 0; nt < 7; ++nt) {
          int col = wn * 112 + nt * 16 + l15;
          float sbv = sbl[col];
          int t = col / 7;
          int j = col - t * 7;
          int slot2 = (t * 8 + j) * 2;
#pragma unroll
          for (int i = 0; i < 4; ++i) {
            int rl = mtl * 16 + gq * 4 + i;
            float p = sigmoidf_(acc[mt][nt][i] + sbv);
            *(_Float16*)(Pl + rl * 1024 + slot2) = (_Float16)p;
          }
        }
      }
    }
    __syncthreads();
    // tree: this wave handles rows wv*4 .. wv*4+3 of the pass; tree t = lane
#pragma unroll
    for (int k = 0; k < 4; ++k) {
      int rl = wv * 4 + k;
      h16x8 v = *(const h16x8*)(Pl + rl * 1024 + lane * 16);
      float p0 = (float)v[0], p1 = (float)v[1], p2 = (float)v[2];
      float p3 = (float)v[3], p4 = (float)v[4], p5 = (float)v[5], p6 = (float)v[6];
      float n0 = 1.f - p0, n1 = 1.f - p1, n2 = 1.f - p2;
      float a00 = n0 * n1, a01 = n0 * p1, a10 = p0 * n2, a11 = p0 * p2;
      float L0 = a00 * (1.f - p3), L1 = a00 * p3;
      float L2 = a01 * (1.f - p4), L3 = a01 * p4;
      float L4 = a10 * (1.f - p5), L5 = a10 * p5;
      float L6 = a11 * (1.f - p6), L7 = a11 * p6;
      float o0 = L0*qreg[0] + L1*qreg[2] + L2*qreg[4] + L3*qreg[6]
               + L4*qreg[8] + L5*qreg[10] + L6*qreg[12] + L7*qreg[14];
      float o1 = L0*qreg[1] + L1*qreg[3] + L2*qreg[5] + L3*qreg[7]
               + L4*qreg[9] + L5*qreg[11] + L6*qreg[13] + L7*qreg[15];
#pragma unroll
      for (int off = 1; off < 64; off <<= 1) {
        o0 += __shfl_xor(o0, off);
        o1 += __shfl_xor(o1, off);
      }
      if (lane == 0) {
        int gr = rg * 32 + rl;
        outl[gr * 2] = o0;
        outl[gr * 2 + 1] = o1;
      }
    }
    __syncthreads();   // tree reads done before next pass overwrites Pl
  }
  if (tid < 256) out[bm0 * 2 + tid] = outl[tid];
}

// ---------------------------------------------------------------------------
extern "C" void kernel_launch(void* const* d_in, const int* in_sizes, int n_in,
                              void* d_out, int out_size, void* d_ws, size_t ws_size,
                              hipStream_t stream)
{
  const float* Xtr = (const float*)d_in[0];
  const float* Xte = (const float*)d_in[1];
  const float* W1  = (const float*)d_in[3];
  const float* b1  = (const float*)d_in[4];
  const float* g1  = (const float*)d_in[5];
  const float* be1 = (const float*)d_in[6];
  const float* W2  = (const float*)d_in[7];
  const float* b2  = (const float*)d_in[8];
  const float* H1  = (const float*)d_in[9];
  const float* hb1 = (const float*)d_in[10];
  const float* g2  = (const float*)d_in[11];
  const float* be2 = (const float*)d_in[12];
  const float* H2  = (const float*)d_in[13];
  const float* hb2 = (const float*)d_in[14];
  const float* H3  = (const float*)d_in[15];
  const float* hb3 = (const float*)d_in[16];
  float* out = (float*)d_out;
  char* ws = (char*)d_ws;

  float* c_accum = (float*)ws;                 // 64 f32
  float* u2      = (float*)(ws + 256);         // 128 f32
  float* sb      = (float*)(ws + 768);         // 448 f32
  float* ll      = (float*)(ws + 2560);        // 1024 f32
  float* tw      = (float*)(ws + 6656);        // 64 f32
  float* q       = (float*)(ws + 6912);        // 1024 f32
  unsigned short* Bsw = (unsigned short*)(ws + 11008); // 448*512 bf16

  hipMemsetAsync(c_accum, 0, 64 * sizeof(float), stream);
  k_train<<<128, 256, 0, stream>>>(Xtr, W1, b1, g1, be1, W2, b2, c_accum);
  k_head<<<1, 128, 0, stream>>>(c_accum, H1, hb1, g2, be2, H2, hb2, u2);
  k_params<<<3608, 256, 0, stream>>>(H3, hb3, u2, Bsw, sb, ll, tw);
  k_qprep<<<1, 64, 0, stream>>>(ll, tw, q);
  k_test<<<256, 512, 0, stream>>>(Xte, Bsw, sb, q, out);
}

// Round 4
// 84.871 us; speedup vs baseline: 2.9479x; 1.1345x over previous
//
#include <hip/hip_runtime.h>
#include <hip/hip_bf16.h>

// Problem constants
#define DD 512
#define HIDN 64
#define NTREE 64
#define NIN 7           // internal nodes
#define PPTC 3607       // NI*D + NI + NL*2
#define TOTP 230912     // PPT*T + T
#define SWROWS 448      // T*NI

typedef __attribute__((ext_vector_type(8))) short bf16x8;
typedef __attribute__((ext_vector_type(4))) float f32x4;
typedef __attribute__((ext_vector_type(8))) _Float16 h16x8;

__device__ __forceinline__ unsigned short f2bf(float f) {
  unsigned u = __float_as_uint(f);
  unsigned r = (u + 0x7FFFu + ((u >> 16) & 1u)) >> 16;   // RNE
  return (unsigned short)r;
}
__device__ __forceinline__ float sigmoidf_(float x) {
  return 1.0f / (1.0f + __expf(-x));
}
__device__ __forceinline__ uint2 pack_bf16x4(float4 v) {
  uint2 pk;
  pk.x = (unsigned)f2bf(v.x) | ((unsigned)f2bf(v.y) << 16);
  pk.y = (unsigned)f2bf(v.z) | ((unsigned)f2bf(v.w) << 16);
  return pk;
}

// ---------------------------------------------------------------------------
// Kernel 1: train path. 256 blocks x 256 thr (4 waves), 32 rows/block.
// Wave grid 2M x 2N. GEMM1 (512->64 bf16 MFMA, reg-pipelined K-chunks) + LN
// (cross-wave partials via LDS) + relu -> GEMM2 (64->64) + relu -> per-block
// column partial sums to c_part[block][64] (no atomics, no memset needed).
// ---------------------------------------------------------------------------
__global__ __launch_bounds__(256) void k_train(
    const float* __restrict__ Xtr, const float* __restrict__ W1,
    const float* __restrict__ b1, const float* __restrict__ g1,
    const float* __restrict__ be1, const float* __restrict__ W2,
    const float* __restrict__ b2, float* __restrict__ c_part)
{
  __shared__ __align__(16) char smem[37888];
  char* Xc  = smem;             // [32][128] bf16 = 8192
  char* W1c = smem + 8192;      // [64][128] bf16 = 16384
  char* Hl  = smem + 24576;     // [32][64] bf16 = 4096
  char* W2l = smem + 28672;     // [64][64] bf16 = 8192
  float* lnb = (float*)(smem + 36864);   // [32][2][2] f32 = 512
  float* cp  = (float*)(smem + 37376);   // [2][64] f32 = 512

  const int tid = threadIdx.x;
  const int lane = tid & 63;
  const int wv = tid >> 6;
  const int l15 = lane & 15;
  const int gq = lane >> 4;
  const int wm = wv >> 1;       // 0..1 (16-row group)
  const int wn = wv & 1;        // 0..1 (32-col group)
  const int rb0 = blockIdx.x * 32;

  const float4* X4g = (const float4*)Xtr;
  const float4* W4g = (const float4*)W1;

  // stage W2 (64x64 fp32 -> bf16, B layout, swizzled)
#pragma unroll
  for (int s = 0; s < 4; ++s) {
    int fidx = tid + s * 256;
    int n = fidx >> 4, kq = fidx & 15;
    float4 v = ((const float4*)W2)[n * 16 + kq];
    uint2 pk = pack_bf16x4(v);
    int off = n * 128 + kq * 8; off ^= (n & 7) << 4;
    *(uint2*)(W2l + off) = pk;
  }

  // staging index precompute
  int xga[4], xo[4];
#pragma unroll
  for (int s = 0; s < 4; ++s) {
    int f = tid + s * 256;                // 1024 float4 (32 rows x 32)
    int m = f >> 5, kq = f & 31;
    xga[s] = (rb0 + m) * 128 + kq;        // + kc*32
    xo[s] = (m * 256 + kq * 8) ^ ((m & 7) << 4);
  }
  int wga[8], wo[8];
#pragma unroll
  for (int s = 0; s < 8; ++s) {
    int f = tid + s * 256;                // 2048 float4 (64 rows x 32)
    int n = f >> 5, kq = f & 31;
    wga[s] = n * 128 + kq;                // + kc*32
    wo[s] = (n * 256 + kq * 8) ^ ((n & 7) << 4);
  }

  f32x4 acc1[2];
#pragma unroll
  for (int nt = 0; nt < 2; ++nt) { f32x4 z = {0.f,0.f,0.f,0.f}; acc1[nt] = z; }

  // prologue: load chunk 0
  float4 xr[4], wr[8];
#pragma unroll
  for (int s = 0; s < 4; ++s) xr[s] = X4g[xga[s]];
#pragma unroll
  for (int s = 0; s < 8; ++s) wr[s] = W4g[wga[s]];

  for (int kc = 0; kc < 4; ++kc) {
    __syncthreads();   // prior chunk's frag reads done
#pragma unroll
    for (int s = 0; s < 4; ++s) *(uint2*)(Xc + xo[s]) = pack_bf16x4(xr[s]);
#pragma unroll
    for (int s = 0; s < 8; ++s) *(uint2*)(W1c + wo[s]) = pack_bf16x4(wr[s]);
    if (kc < 3) {
      int ko = (kc + 1) * 32;
#pragma unroll
      for (int s = 0; s < 4; ++s) xr[s] = X4g[xga[s] + ko];
#pragma unroll
      for (int s = 0; s < 8; ++s) wr[s] = W4g[wga[s] + ko];
    }
    __syncthreads();   // tile ready
#pragma unroll
    for (int ks = 0; ks < 4; ++ks) {
      int arow = wm * 16 + l15;
      int aoff = (arow * 256 + ks * 64 + gq * 16) ^ ((arow & 7) << 4);
      bf16x8 afr = *(const bf16x8*)(Xc + aoff);
#pragma unroll
      for (int nt = 0; nt < 2; ++nt) {
        int brow = wn * 32 + nt * 16 + l15;
        int boff = (brow * 256 + ks * 64 + gq * 16) ^ ((brow & 7) << 4);
        bf16x8 bfr = *(const bf16x8*)(W1c + boff);
        acc1[nt] = __builtin_amdgcn_mfma_f32_16x16x32_bf16(afr, bfr, acc1[nt], 0, 0, 0);
      }
    }
  }

  // per-row LN partials over this wave's 32 cols
  float b1v[2], g1v[2], be1v[2], b2v[2];
#pragma unroll
  for (int nt = 0; nt < 2; ++nt) {
    int c = wn * 32 + nt * 16 + l15;
    b1v[nt] = b1[c]; g1v[nt] = g1[c]; be1v[nt] = be1[c]; b2v[nt] = b2[c];
  }
  float yv[2][4], s_[4], q_[4];
#pragma unroll
  for (int i = 0; i < 4; ++i) {
    float s = 0.f, q = 0.f;
#pragma unroll
    for (int nt = 0; nt < 2; ++nt) {
      float y = acc1[nt][i] + b1v[nt];
      yv[nt][i] = y; s += y; q += y * y;
    }
    s_[i] = s; q_[i] = q;
  }
#pragma unroll
  for (int off = 1; off < 16; off <<= 1) {
#pragma unroll
    for (int i = 0; i < 4; ++i) {
      s_[i] += __shfl_xor(s_[i], off);
      q_[i] += __shfl_xor(q_[i], off);
    }
  }
  if (l15 == 0) {
#pragma unroll
    for (int i = 0; i < 4; ++i) {
      int row = wm * 16 + gq * 4 + i;
      float2 sv; sv.x = s_[i]; sv.y = q_[i];
      *(float2*)(lnb + (row * 2 + wn) * 2) = sv;
    }
  }
  __syncthreads();
  // combine both wn halves, apply LN+relu, write h to Hl (bf16, swizzled)
#pragma unroll
  for (int i = 0; i < 4; ++i) {
    int row = wm * 16 + gq * 4 + i;
    float2 e0 = *(float2*)(lnb + (row * 2 + 0) * 2);
    float2 e1 = *(float2*)(lnb + (row * 2 + 1) * 2);
    float m = (e0.x + e1.x) * (1.0f / 64.0f);
    float var = (e0.y + e1.y) * (1.0f / 64.0f) - m * m;
    float rstd = rsqrtf(var + 1e-5f);
#pragma unroll
    for (int nt = 0; nt < 2; ++nt) {
      float h = (yv[nt][i] - m) * rstd * g1v[nt] + be1v[nt];
      h = fmaxf(h, 0.0f);
      int col = wn * 32 + nt * 16 + l15;
      int off2 = (row * 128 + col * 2) ^ ((row & 7) << 4);
      *(unsigned short*)(Hl + off2) = f2bf(h);
    }
  }
  __syncthreads();

  // GEMM2: z = h @ W2^T, 16 rows x 32 cols per wave
  f32x4 acc2[2];
#pragma unroll
  for (int nt = 0; nt < 2; ++nt) { f32x4 z = {0.f,0.f,0.f,0.f}; acc2[nt] = z; }
#pragma unroll
  for (int ks = 0; ks < 2; ++ks) {
    int arow = wm * 16 + l15;
    int aoff = (arow * 128 + ks * 64 + gq * 16) ^ ((arow & 7) << 4);
    bf16x8 afr = *(const bf16x8*)(Hl + aoff);
#pragma unroll
    for (int nt = 0; nt < 2; ++nt) {
      int brow = wn * 32 + nt * 16 + l15;
      int boff = (brow * 128 + ks * 64 + gq * 16) ^ ((brow & 7) << 4);
      bf16x8 bfr = *(const bf16x8*)(W2l + boff);
      acc2[nt] = __builtin_amdgcn_mfma_f32_16x16x32_bf16(afr, bfr, acc2[nt], 0, 0, 0);
    }
  }
  // relu(z+b2), column sums over this wave's 16 rows
  float cs[2];
#pragma unroll
  for (int nt = 0; nt < 2; ++nt) {
    float s = 0.f;
#pragma unroll
    for (int i = 0; i < 4; ++i) s += fmaxf(acc2[nt][i] + b2v[nt], 0.0f);
    cs[nt] = s;
  }
#pragma unroll
  for (int nt = 0; nt < 2; ++nt) {
    cs[nt] += __shfl_xor(cs[nt], 16);
    cs[nt] += __shfl_xor(cs[nt], 32);
  }
  if (lane < 16) {
#pragma unroll
    for (int nt = 0; nt < 2; ++nt)
      cp[wm * 64 + wn * 32 + nt * 16 + lane] = cs[nt];
  }
  __syncthreads();
  if (tid < 64) c_part[blockIdx.x * 64 + tid] = cp[tid] + cp[64 + tid];
}

// ---------------------------------------------------------------------------
// Kernel 2: reduce c partials + head MLP (fp32, tiny). 1 block x 128 threads.
// ---------------------------------------------------------------------------
__global__ __launch_bounds__(128) void k_head(
    const float* __restrict__ c_part,
    const float* __restrict__ H1, const float* __restrict__ hb1,
    const float* __restrict__ g2, const float* __restrict__ be2,
    const float* __restrict__ H2, const float* __restrict__ hb2,
    float* __restrict__ u2out)
{
  __shared__ float clds[64];
  __shared__ float u1lds[128];
  __shared__ float red[4];
  int tid = threadIdx.x;
  if (tid < 64) {
    float s0 = 0.f, s1 = 0.f, s2 = 0.f, s3 = 0.f;
    for (int b = 0; b < 256; b += 4) {
      s0 += c_part[(b + 0) * 64 + tid];
      s1 += c_part[(b + 1) * 64 + tid];
      s2 += c_part[(b + 2) * 64 + tid];
      s3 += c_part[(b + 3) * 64 + tid];
    }
    clds[tid] = (s0 + s1 + s2 + s3) * (1.0f / 8192.0f);
  }
  __syncthreads();
  float a0 = 0.f, a1 = 0.f, a2p = 0.f, a3 = 0.f;
  for (int k = 0; k < 64; k += 4) {
    a0 += clds[k + 0] * H1[tid * 64 + k + 0];
    a1 += clds[k + 1] * H1[tid * 64 + k + 1];
    a2p += clds[k + 2] * H1[tid * 64 + k + 2];
    a3 += clds[k + 3] * H1[tid * 64 + k + 3];
  }
  float acc = hb1[tid] + ((a0 + a1) + (a2p + a3));
  float s = acc, q = acc * acc;
#pragma unroll
  for (int off = 1; off < 64; off <<= 1) { s += __shfl_xor(s, off); q += __shfl_xor(q, off); }
  int wv = tid >> 6;
  if ((tid & 63) == 0) { red[wv * 2] = s; red[wv * 2 + 1] = q; }
  __syncthreads();
  float S = red[0] + red[2], Q = red[1] + red[3];
  float m = S * (1.0f / 128.0f);
  float var = Q * (1.0f / 128.0f) - m * m;
  float rstd = rsqrtf(var + 1e-5f);
  float u1 = fmaxf((acc - m) * rstd * g2[tid] + be2[tid], 0.0f);
  u1lds[tid] = u1;
  __syncthreads();
  float c0 = 0.f, c1 = 0.f, c2 = 0.f, c3 = 0.f;
  for (int k = 0; k < 128; k += 4) {
    c0 += u1lds[k + 0] * H2[tid * 128 + k + 0];
    c1 += u1lds[k + 1] * H2[tid * 128 + k + 1];
    c2 += u1lds[k + 2] * H2[tid * 128 + k + 2];
    c3 += u1lds[k + 3] * H2[tid * 128 + k + 3];
  }
  u2out[tid] = fmaxf(hb2[tid] + ((c0 + c1) + (c2 + c3)), 0.0f);
}

// ---------------------------------------------------------------------------
// Kernel 3: params = u2 @ H3^T + hb3, routed to sw(bf16)/sb/ll/tw.
// ---------------------------------------------------------------------------
__global__ __launch_bounds__(256) void k_params(
    const float* __restrict__ H3, const float* __restrict__ hb3,
    const float* __restrict__ u2,
    unsigned short* __restrict__ Bsw, float* __restrict__ sb,
    float* __restrict__ ll, float* __restrict__ tw)
{
  __shared__ float u2l[128];
  int tid = threadIdx.x;
  if (tid < 128) u2l[tid] = u2[tid];
  __syncthreads();
  int row = blockIdx.x * 64 + (tid >> 2);
  int sub = tid & 3;
  float acc = 0.0f;
  const float4* H4 = (const float4*)H3;
#pragma unroll
  for (int j = 0; j < 8; ++j) {
    int f = j * 4 + sub;
    float4 v = H4[row * 32 + f];
    acc += v.x * u2l[f * 4] + v.y * u2l[f * 4 + 1] + v.z * u2l[f * 4 + 2] + v.w * u2l[f * 4 + 3];
  }
  acc += __shfl_xor(acc, 1);
  acc += __shfl_xor(acc, 2);
  if (sub == 0) {
    float val = acc + hb3[row];
    if (row >= 230848) {
      tw[row - 230848] = val;
    } else {
      int t = row / PPTC;
      int r = row - t * PPTC;
      if (r < 3584) {
        int n = r >> 9, d = r & 511;
        Bsw[(t * 7 + n) * 512 + d] = f2bf(val);
      } else if (r < 3591) {
        sb[t * 7 + (r - 3584)] = val;
      } else {
        ll[t * 16 + (r - 3591)] = val;
      }
    }
  }
}

// ---------------------------------------------------------------------------
// Kernel 4: q[t][l][c] = 2 * softmax(tw)[t] * softmax(ll[t,l,:])[c]
// ---------------------------------------------------------------------------
__global__ __launch_bounds__(64) void k_qprep(
    const float* __restrict__ ll, const float* __restrict__ tw,
    float* __restrict__ q)
{
  int t = threadIdx.x;
  float x = tw[t];
  float m = x;
#pragma unroll
  for (int off = 1; off < 64; off <<= 1) m = fmaxf(m, __shfl_xor(m, off));
  float e = __expf(x - m);
  float s = e;
#pragma unroll
  for (int off = 1; off < 64; off <<= 1) s += __shfl_xor(s, off);
  float w = e / s;
#pragma unroll
  for (int l = 0; l < 8; ++l) {
    float a = ll[t * 16 + l * 2], b = ll[t * 16 + l * 2 + 1];
    float mm = fmaxf(a, b);
    float e0 = __expf(a - mm), e1 = __expf(b - mm);
    float inv = 2.0f * w / (e0 + e1);
    q[t * 16 + l * 2] = e0 * inv;
    q[t * 16 + l * 2 + 1] = e1 * inv;
  }
}

// ---------------------------------------------------------------------------
// Kernel 5: main inference. 256 blocks x 512 thr (8 waves), BM=128, BN=448,
// BK=32. Double-buffered LDS, ONE barrier per K-step; next tile written to
// the idle buffer during compute; global loads issued ~2 phases ahead.
// B-staging tail is wave-uniform guarded (tid<256) — no same-address storm.
// ---------------------------------------------------------------------------
__global__ __launch_bounds__(512) void k_test(
    const float* __restrict__ Xt, const unsigned short* __restrict__ Bsw,
    const float* __restrict__ sb, const float* __restrict__ q,
    float* __restrict__ out)
{
  __shared__ __align__(16) char smem[76544];
  char* Xb0 = smem;                       // [128][32] bf16 = 8192
  char* Xb1 = smem + 8192;                // 8192
  char* Bb0 = smem + 16384;               // [448][32] bf16 = 28672
  char* Bb1 = smem + 45056;               // 28672 -> 73728
  char* Pl  = smem + 16384;               // p tile alias: 32 rows x 1024 B
  float* sbl  = (float*)(smem + 73728);   // 448 f32 -> 75520
  float* outl = (float*)(smem + 75520);   // 256 f32 -> 76544

  const int tid = threadIdx.x;
  const int lane = tid & 63;
  const int wv = tid >> 6;
  const int l15 = lane & 15;
  const int gq = lane >> 4;
  const int wm = wv >> 2;        // 0..1 (64-row group)
  const int wn = wv & 3;         // 0..3 (112-col group)
  const int bm0 = blockIdx.x * 128;
  const bool btail = (tid < 256);   // wave-uniform (waves 0-3)

  if (tid < 448) sbl[tid] = sb[tid];

  // q in registers: tree t = lane
  float qreg[16];
  {
    const float4* q4 = (const float4*)q;
#pragma unroll
    for (int j = 0; j < 4; ++j) {
      float4 v = q4[lane * 4 + j];
      qreg[j * 4] = v.x; qreg[j * 4 + 1] = v.y; qreg[j * 4 + 2] = v.z; qreg[j * 4 + 3] = v.w;
    }
  }

  // staging addresses
  const int xm = tid >> 3, xk = tid & 7;
  const int xg0 = (bm0 + xm) * 128 + xk;            // + kt*8 (float4 idx)
  const int xg1 = (bm0 + xm + 64) * 128 + xk;
  const int xo0 = (xm * 64 + xk * 8) ^ ((xm & 7) << 4);
  const int xo1 = ((xm + 64) * 64 + xk * 8) ^ ((xm & 7) << 4);

  int bg[4], bo[4];
#pragma unroll
  for (int s = 0; s < 4; ++s) {
    int idx = tid + s * 512;               // 0..2047; only <1792 valid
    int n = idx >> 2, part = idx & 3;
    bg[s] = n * 64 + part;                 // + kt*4 (uint4 idx)
    bo[s] = (n * 64 + part * 16) ^ ((n & 7) << 4);
  }

  // frag read offsets
  int aoffs[4], boffs[7];
#pragma unroll
  for (int mt = 0; mt < 4; ++mt) {
    int r = wm * 64 + mt * 16 + l15;
    aoffs[mt] = (r * 64 + gq * 16) ^ ((r & 7) << 4);
  }
#pragma unroll
  for (int nt = 0; nt < 7; ++nt) {
    int r = wn * 112 + nt * 16 + l15;
    boffs[nt] = (r * 64 + gq * 16) ^ ((r & 7) << 4);
  }

  f32x4 acc[4][7];
#pragma unroll
  for (int mt = 0; mt < 4; ++mt)
#pragma unroll
    for (int nt = 0; nt < 7; ++nt) { f32x4 z = {0.f,0.f,0.f,0.f}; acc[mt][nt] = z; }

  const float4* X4 = (const float4*)Xt;
  const uint4* B4 = (const uint4*)Bsw;

#define LOADX(xa, xb, kt) do { xa = X4[xg0 + (kt) * 8]; xb = X4[xg1 + (kt) * 8]; } while (0)
#define LOADB(b0_, b1_, b2_, b3_, kt) do { \
    b0_ = B4[bg[0] + (kt) * 4]; b1_ = B4[bg[1] + (kt) * 4]; b2_ = B4[bg[2] + (kt) * 4]; \
    if (btail) b3_ = B4[bg[3] + (kt) * 4]; } while (0)
#define STORET(Xb, Bb, xa, xb, b0_, b1_, b2_, b3_) do { \
    *(uint2*)((Xb) + xo0) = pack_bf16x4(xa); \
    *(uint2*)((Xb) + xo1) = pack_bf16x4(xb); \
    *(uint4*)((Bb) + bo[0]) = b0_; \
    *(uint4*)((Bb) + bo[1]) = b1_; \
    *(uint4*)((Bb) + bo[2]) = b2_; \
    if (btail) *(uint4*)((Bb) + bo[3]) = b3_; } while (0)
#define COMPUTE(Xb, Bb) do { \
    bf16x8 afr[4]; \
    _Pragma("unroll") \
    for (int mt = 0; mt < 4; ++mt) afr[mt] = *(const bf16x8*)((Xb) + aoffs[mt]); \
    _Pragma("unroll") \
    for (int nt = 0; nt < 7; ++nt) { \
      bf16x8 bfr = *(const bf16x8*)((Bb) + boffs[nt]); \
      _Pragma("unroll") \
      for (int mt = 0; mt < 4; ++mt) \
        acc[mt][nt] = __builtin_amdgcn_mfma_f32_16x16x32_bf16(afr[mt], bfr, acc[mt][nt], 0, 0, 0); \
    } } while (0)

  float4 xra, xrb, xca, xcb;
  uint4 ba0, ba1, ba2, ba3, bb0, bb1, bb2, bb3;

  // prologue: kt=0 -> buf0 ; kt=1 -> regs(b)
  LOADX(xra, xca, 0);
  LOADB(ba0, ba1, ba2, ba3, 0);
  STORET(Xb0, Bb0, xra, xca, ba0, ba1, ba2, ba3);
  LOADX(xrb, xcb, 1);
  LOADB(bb0, bb1, bb2, bb3, 1);
  __syncthreads();

  for (int kt2 = 0; kt2 < 16; kt2 += 2) {
    // even phase: compute buf0; write regs(b)=kt2+1 -> buf1; load kt2+2 -> regs(a)
    STORET(Xb1, Bb1, xrb, xcb, bb0, bb1, bb2, bb3);
    if (kt2 + 2 < 16) {
      LOADX(xra, xca, kt2 + 2);
      LOADB(ba0, ba1, ba2, ba3, kt2 + 2);
    }
    COMPUTE(Xb0, Bb0);
    __syncthreads();
    // odd phase: compute buf1; write regs(a)=kt2+2 -> buf0; load kt2+3 -> regs(b)
    if (kt2 + 2 < 16) {
      STORET(Xb0, Bb0, xra, xca, ba0, ba1, ba2, ba3);
      if (kt2 + 3 < 16) {
        LOADX(xrb, xcb, kt2 + 3);
        LOADB(bb0, bb1, bb2, bb3, kt2 + 3);
      }
    }
    COMPUTE(Xb1, Bb1);
    __syncthreads();
  }

  // ---- fused sigmoid + soft-tree + leaf/tree mixing, 4 passes of 32 rows.
#pragma unroll
  for (int rg = 0; rg < 4; ++rg) {
    if (wm == (rg >> 1)) {
#pragma unroll
      for (int mtl = 0; mtl < 2; ++mtl) {
        const int mt = (rg & 1) * 2 + mtl;
#pragma unroll
        for (int nt = 0; nt < 7; ++nt) {
          int col = wn * 112 + nt * 16 + l15;
          float sbv = sbl[col];
          int t = col / 7;
          int j = col - t * 7;
          int slot2 = (t * 8 + j) * 2;
#pragma unroll
          for (int i = 0; i < 4; ++i) {
            int rl = mtl * 16 + gq * 4 + i;
            float p = sigmoidf_(acc[mt][nt][i] + sbv);
            *(_Float16*)(Pl + rl * 1024 + slot2) = (_Float16)p;
          }
        }
      }
    }
    __syncthreads();
#pragma unroll
    for (int k = 0; k < 4; ++k) {
      int rl = wv * 4 + k;
      h16x8 v = *(const h16x8*)(Pl + rl * 1024 + lane * 16);
      float p0 = (float)v[0], p1 = (float)v[1], p2 = (float)v[2];
      float p3 = (float)v[3], p4 = (float)v[4], p5 = (float)v[5], p6 = (float)v[6];
      float n0 = 1.f - p0, n1 = 1.f - p1, n2 = 1.f - p2;
      float a00 = n0 * n1, a01 = n0 * p1, a10 = p0 * n2, a11 = p0 * p2;
      float L0 = a00 * (1.f - p3), L1 = a00 * p3;
      float L2 = a01 * (1.f - p4), L3 = a01 * p4;
      float L4 = a10 * (1.f - p5), L5 = a10 * p5;
      float L6 = a11 * (1.f - p6), L7 = a11 * p6;
      float o0 = L0*qreg[0] + L1*qreg[2] + L2*qreg[4] + L3*qreg[6]
               + L4*qreg[8] + L5*qreg[10] + L6*qreg[12] + L7*qreg[14];
      float o1 = L0*qreg[1] + L1*qreg[3] + L2*qreg[5] + L3*qreg[7]
               + L4*qreg[9] + L5*qreg[11] + L6*qreg[13] + L7*qreg[15];
#pragma unroll
      for (int off = 1; off < 64; off <<= 1) {
        o0 += __shfl_xor(o0, off);
        o1 += __shfl_xor(o1, off);
      }
      if (lane == 0) {
        int gr = rg * 32 + rl;
        outl[gr * 2] = o0;
        outl[gr * 2 + 1] = o1;
      }
    }
    __syncthreads();
  }
  if (tid < 256) out[bm0 * 2 + tid] = outl[tid];
#undef LOADX
#undef LOADB
#undef STORET
#undef COMPUTE
}

// ---------------------------------------------------------------------------
extern "C" void kernel_launch(void* const* d_in, const int* in_sizes, int n_in,
                              void* d_out, int out_size, void* d_ws, size_t ws_size,
                              hipStream_t stream)
{
  const float* Xtr = (const float*)d_in[0];
  const float* Xte = (const float*)d_in[1];
  const float* W1  = (const float*)d_in[3];
  const float* b1  = (const float*)d_in[4];
  const float* g1  = (const float*)d_in[5];
  const float* be1 = (const float*)d_in[6];
  const float* W2  = (const float*)d_in[7];
  const float* b2  = (const float*)d_in[8];
  const float* H1  = (const float*)d_in[9];
  const float* hb1 = (const float*)d_in[10];
  const float* g2  = (const float*)d_in[11];
  const float* be2 = (const float*)d_in[12];
  const float* H2  = (const float*)d_in[13];
  const float* hb2 = (const float*)d_in[14];
  const float* H3  = (const float*)d_in[15];
  const float* hb3 = (const float*)d_in[16];
  float* out = (float*)d_out;
  char* ws = (char*)d_ws;

  float* c_part = (float*)ws;                  // 256*64 f32 = 65536 B
  float* u2     = (float*)(ws + 65536);        // 128 f32
  float* sb     = (float*)(ws + 66048);        // 448 f32
  float* ll     = (float*)(ws + 67840);        // 1024 f32
  float* tw     = (float*)(ws + 71936);        // 64 f32
  float* q      = (float*)(ws + 72192);        // 1024 f32
  unsigned short* Bsw = (unsigned short*)(ws + 76288); // 448*512 bf16

  k_train<<<256, 256, 0, stream>>>(Xtr, W1, b1, g1, be1, W2, b2, c_part);
  k_head<<<1, 128, 0, stream>>>(c_part, H1, hb1, g2, be2, H2, hb2, u2);
  k_params<<<3608, 256, 0, stream>>>(H3, hb3, u2, Bsw, sb, ll, tw);
  k_qprep<<<1, 64, 0, stream>>>(ll, tw, q);
  k_test<<<256, 512, 0, stream>>>(Xte, Bsw, sb, q, out);
}